// Round 12
// baseline (27.563 us; speedup 1.0000x reference)
//
#include <hip/hip_runtime.h>

#define C_IN  32
#define O_OUT 48
#define H_IN  96
#define W_IN  96
#define H_OUT 192
#define W_OUT 192
#define HW_IN (H_IN * W_IN)
#define NCBLK 384               // compute blocks: 2 b x 96 rows x 2 half
#define NFBLK 16                // frame blocks: 2 b x 2 side x 4 o-groups
#define WPK_VAR 24576           // ushorts per variant

typedef __attribute__((ext_vector_type(8))) short bf16x8;
typedef __attribute__((ext_vector_type(4))) float f32x4;

__device__ __forceinline__ unsigned short f2bf(float f) {
    union { float f; unsigned u; } v; v.f = f;
    unsigned u = v.u + 0x7FFFu + ((v.u >> 16) & 1u);
    return (unsigned short)(u >> 16);
}

// ---------------------------------------------------------------------------
// Kernel 1 (6 blocks): prescaled MFMA A-fragments, 3 row-edge variants.
//   var 0: interior (both row-taps), var 1: ho=0 (a1 tap absent),
//   var 2: ho=191 (a0 tap absent). Norm folded over PRESENT taps only ->
//   main computes every output row exactly; only wo in {0,191} left to frame.
// Layout: wpk[var][cl][ts][mt][g][o16][e]  (o=mt*16+o16, c=g*8+e), so a
// wave's fragment load is lane-consecutive (g*128 + n16*8) -> fully coalesced.
// Tap map (ts=a*2+d), pe=0: a0->i=1, a1->i=3 | pe=1: a0->i=0, a1->i=2
//                     po=0: d0->j=1, d1->j=3 | po=1: d0->j=0, d1->j=2
// ---------------------------------------------------------------------------
__global__ __launch_bounds__(256) void nct_wpk(
    const float* __restrict__ weight,  // [48,32,4,4]
    unsigned short* __restrict__ wpk)  // [3][24576]
{
    const int oc = blockIdx.x * 256 + threadIdx.x;   // 0..1535
    if (oc >= O_OUT * C_IN) return;
    const int o = oc >> 5, c = oc & 31;
    const float* wc = weight + (size_t)oc * 16;
    float w[16];
    #pragma unroll
    for (int i = 0; i < 16; ++i) w[i] = wc[i];

    const int mt = o >> 4, o16 = o & 15, g = c >> 3, e = c & 7;
    const int base_gc = g * 128 + o16 * 8 + e;

    #pragma unroll
    for (int var = 0; var < 3; ++var) {
        const float m0 = (var == 2) ? 0.f : 1.f;   // a0 tap present?
        const float m1 = (var == 1) ? 0.f : 1.f;   // a1 tap present?
        #pragma unroll
        for (int cl = 0; cl < 4; ++cl) {
            const int pe = cl >> 1, po = cl & 1;
            // row-tap vectors: wa0 = row (pe?0:1), wa1 = row (pe?2:3)
            const float* wa0 = w + (pe ? 0 : 4);
            const float* wa1 = w + (pe ? 8 : 12);
            const int j0 = po ? 0 : 1;   // d0 col tap
            const int j1 = po ? 2 : 3;   // d1 col tap
            const float r = 1.f / (m0 * (wa0[j0] + wa0[j1]) + m1 * (wa1[j0] + wa1[j1]));
            const float v[4] = { m0 * wa0[j0] * r, m0 * wa0[j1] * r,
                                 m1 * wa1[j0] * r, m1 * wa1[j1] * r };
            #pragma unroll
            for (int ts = 0; ts < 4; ++ts)
                wpk[(size_t)var * WPK_VAR + (size_t)(((cl * 4 + ts) * 3 + mt) * 512) + base_gc] = f2bf(v[ts]);
        }
    }
}

// ---------------------------------------------------------------------------
// Kernel 2, two block roles.
// Compute blocks [0,384): (b,row,half). Phase A transposes the 3x50x32 x-slab
// to LDS (bf16). Each of the 6 waves (pe,mt) loads its 8 A-fragments from wpk
// (variant by row-edge class) -- coalesced 16B/lane. MFMA gives exact values
// for ALL rows; wo in {0,191} excluded by store predicates.
// Frame blocks [384,400): border columns wo in {0,191}, full ho 0..191,
// from an LDS-staged x column (no cache-line scatter).
// ---------------------------------------------------------------------------
__global__ __launch_bounds__(384) void nct_main(
    const float* __restrict__ x,       // [2,32,96,96]
    const unsigned short* __restrict__ wpk,
    const float* __restrict__ weight,  // [48,32,4,4] (frame path only)
    const float* __restrict__ bias,    // [48]
    float* __restrict__ out)           // [2,48,192,192]
{
    __shared__ __align__(16) unsigned char smem[12288];
    const int blk = blockIdx.x;
    const int tid = threadIdx.x;

    if (blk < NCBLK) {
        auto xs = (unsigned short (*)[52][32])smem;   // [3][52][32] bf16

        int Wd = blk;
        const int half = Wd & 1; Wd >>= 1;
        const int row  = Wd % 96;
        const int b    = Wd / 96;
        const int c0   = half * 48;

        const int r3[3] = { (row > 0) ? row - 1 : 0, row, (row < H_IN - 1) ? row + 1 : H_IN - 1 };

        // ---- phase A: transpose 3 rows x 50 cols x 32 c into LDS ----
        for (int tau = tid; tau < 600; tau += 384) {
            const int r   = tau / 200;
            const int rem = tau - r * 200;
            const int pix = rem >> 2;
            const int cg  = rem & 3;
            int gcol = c0 - 1 + pix;
            gcol = (gcol < 0) ? 0 : ((gcol > W_IN - 1) ? W_IN - 1 : gcol);
            const float* src = x + (size_t)(b * C_IN + cg * 8) * HW_IN + r3[r] * W_IN + gcol;
            unsigned pk[4];
            #pragma unroll
            for (int k = 0; k < 4; ++k) {
                const float f0 = src[(size_t)(2 * k)     * HW_IN];
                const float f1 = src[(size_t)(2 * k + 1) * HW_IN];
                pk[k] = (unsigned)f2bf(f0) | ((unsigned)f2bf(f1) << 16);
            }
            *(uint4*)(&xs[r][pix][cg * 8]) = make_uint4(pk[0], pk[1], pk[2], pk[3]);
        }

        // ---- per-wave A-fragment load (coalesced from wpk) ----
        const int lane = tid & 63;
        const int wid  = tid >> 6;     // 0..5
        const int pe = wid & 1, mt = wid >> 1;
        const int g = lane >> 4, n16 = lane & 15;

        const bool etop = (pe == 0 && row == 0);
        const bool ebot = (pe == 1 && row == H_IN - 1);
        const int  var  = etop ? 1 : (ebot ? 2 : 0);
        const unsigned short* wp = wpk + (size_t)var * WPK_VAR + g * 128 + n16 * 8;

        bf16x8 A[2][4];
        #pragma unroll
        for (int po = 0; po < 2; ++po)
            #pragma unroll
            for (int ts = 0; ts < 4; ++ts)
                A[po][ts] = *(const bf16x8*)(wp + (size_t)((((pe * 2 + po) * 4 + ts) * 3 + mt) * 512));

        const float4 bv4 = *(const float4*)(bias + mt * 16 + 4 * g);

        __syncthreads();

        const int lr0 = pe ? 2 : 1;
        const int lr1 = pe ? 1 : 0;
        const int ho  = 2 * row + pe;

        #pragma unroll
        for (int nt = 0; nt < 3; ++nt) {
            const int lp = nt * 16 + n16 + 1;

            const bf16x8 B00 = *(const bf16x8*)(&xs[lr0][lp][g * 8]);
            const bf16x8 B0m = *(const bf16x8*)(&xs[lr0][lp - 1][g * 8]);
            const bf16x8 B0p = *(const bf16x8*)(&xs[lr0][lp + 1][g * 8]);
            const bf16x8 B10 = *(const bf16x8*)(&xs[lr1][lp][g * 8]);
            const bf16x8 B1m = *(const bf16x8*)(&xs[lr1][lp - 1][g * 8]);
            const bf16x8 B1p = *(const bf16x8*)(&xs[lr1][lp + 1][g * 8]);

            f32x4 a0 = {0.f, 0.f, 0.f, 0.f}, a1 = {0.f, 0.f, 0.f, 0.f};
            a0 = __builtin_amdgcn_mfma_f32_16x16x32_bf16(A[0][0], B00, a0, 0, 0, 0);
            a0 = __builtin_amdgcn_mfma_f32_16x16x32_bf16(A[0][1], B0m, a0, 0, 0, 0);
            a0 = __builtin_amdgcn_mfma_f32_16x16x32_bf16(A[0][2], B10, a0, 0, 0, 0);
            a0 = __builtin_amdgcn_mfma_f32_16x16x32_bf16(A[0][3], B1m, a0, 0, 0, 0);
            a1 = __builtin_amdgcn_mfma_f32_16x16x32_bf16(A[1][0], B0p, a1, 0, 0, 0);
            a1 = __builtin_amdgcn_mfma_f32_16x16x32_bf16(A[1][1], B00, a1, 0, 0, 0);
            a1 = __builtin_amdgcn_mfma_f32_16x16x32_bf16(A[1][2], B1p, a1, 0, 0, 0);
            a1 = __builtin_amdgcn_mfma_f32_16x16x32_bf16(A[1][3], B10, a1, 0, 0, 0);

            const int col = c0 + nt * 16 + n16;
            #pragma unroll
            for (int r = 0; r < 4; ++r) {
                const int oo = mt * 16 + 4 * g + r;
                const float v0 = a0[r] + bv4[r];
                const float v1 = a1[r] + bv4[r];
                float* p = out + ((size_t)(b * O_OUT + oo) * H_OUT + ho) * W_OUT + 2 * col;
                if (col == 0)             p[1] = v1;          // wo=0 is col-frame
                else if (col == W_IN - 1) p[0] = v0;          // wo=191 is col-frame
                else                      *(float2*)p = make_float2(v0, v1);
            }
        }
    } else {
        // ---- frame: border columns wo in {0,191}, ho 0..191 (corners incl.) ----
        float* xcol = (float*)smem;              // [32][96]

        const int fb   = blk - NCBLK;            // 0..15
        const int b    = fb >> 3;
        const int side = (fb >> 2) & 1;
        const int og   = fb & 3;

        const int o_loc  = tid >> 5;             // 0..11
        const int ho_loc = tid & 31;             // 0..31
        const int o      = og * 12 + o_loc;
        const int wo     = side ? 191 : 0;
        const int colx   = side ? 95 : 0;
        const int pe     = ho_loc & 1;
        const int jstar  = side ? 2 : 1;

        // stage x[:, :, :, colx] -> LDS [c][row]
        for (int idx = tid; idx < C_IN * H_IN; idx += 384) {
            const int c = idx / H_IN;
            const int r = idx - c * H_IN;
            xcol[c * H_IN + r] = x[(size_t)(b * C_IN + c) * HW_IN + r * W_IN + colx];
        }
        __syncthreads();

        int   rA[6], rB[6];
        float mBf[6];
        #pragma unroll
        for (int k = 0; k < 6; ++k) {
            const int ho = ho_loc + 32 * k;
            const int s  = ho >> 1;
            rA[k] = s;
            if (pe) { const bool m = (s + 1 < H_IN); rB[k] = m ? s + 1 : H_IN - 1; mBf[k] = m ? 1.f : 0.f; }
            else    { const bool m = (s > 0);        rB[k] = m ? s - 1 : 0;        mBf[k] = m ? 1.f : 0.f; }
        }

        const int iA = pe ? 8 : 4;    // w row-tap base for rA (i=2 / i=1)
        const int iB = pe ? 0 : 12;   // for rB (i=0 / i=3)

        float acc[6] = {0.f, 0.f, 0.f, 0.f, 0.f, 0.f};
        const float* wb = weight + (size_t)o * (C_IN * 16);

        for (int c = 0; c < C_IN; ++c) {
            const float wA = wb[c * 16 + iA + jstar];
            const float wB = wb[c * 16 + iB + jstar];
            const float rn_int  = __builtin_amdgcn_rcpf(wA + wB);
            const float rn_edge = __builtin_amdgcn_rcpf(wA);
            const float* xc = xcol + c * H_IN;
            #pragma unroll
            for (int k = 0; k < 6; ++k) {
                const float xA = xc[rA[k]];
                const float xB = xc[rB[k]];
                const float rn = (mBf[k] != 0.f) ? rn_int : rn_edge;
                acc[k] += (wA * xA + mBf[k] * (wB * xB)) * rn;
            }
        }

        const float bv = bias[o];
        #pragma unroll
        for (int k = 0; k < 6; ++k) {
            const int ho = ho_loc + 32 * k;
            out[((size_t)(b * O_OUT + o) * H_OUT + ho) * W_OUT + wo] = acc[k] + bv;
        }
    }
}

extern "C" void kernel_launch(void* const* d_in, const int* in_sizes, int n_in,
                              void* d_out, int out_size, void* d_ws, size_t ws_size,
                              hipStream_t stream) {
    const float* x    = (const float*)d_in[0];
    const float* w    = (const float*)d_in[1];
    const float* bias = (const float*)d_in[2];
    float* out = (float*)d_out;

    unsigned short* wpk = (unsigned short*)d_ws;   // 3*24576 ushorts = 144 KB

    dim3 b256(256, 1, 1);
    dim3 gw(6, 1, 1);
    hipLaunchKernelGGL(nct_wpk, gw, b256, 0, stream, w, wpk);

    dim3 b384(384, 1, 1);
    dim3 gm(NCBLK + NFBLK, 1, 1);                  // 400 blocks
    hipLaunchKernelGGL(nct_main, gm, b384, 0, stream, x, wpk, w, bias, out);
}

// Round 13
// 26.414 us; speedup vs baseline: 1.0435x; 1.0435x over previous
//
#include <hip/hip_runtime.h>

#define C_IN  32
#define O_OUT 48
#define H_IN  96
#define W_IN  96
#define H_OUT 192
#define W_OUT 192
#define HW_IN (H_IN * W_IN)
#define NCBLK 384               // compute blocks: 2 b x 96 rows x 2 half
#define NFBLK 16                // frame blocks: 2 b x 2 side x 4 o-groups
#define LPAD  40                // LDS row stride (elems): 80B -> b128 bank floor

typedef __attribute__((ext_vector_type(8))) short bf16x8;
typedef __attribute__((ext_vector_type(4))) float f32x4;

__device__ __forceinline__ unsigned short f2bf(float f) {
    union { float f; unsigned u; } v; v.f = f;
    unsigned u = v.u + 0x7FFFu + ((v.u >> 16) & 1u);
    return (unsigned short)(u >> 16);
}

// ---------------------------------------------------------------------------
// Single kernel, two block roles.
//
// Compute blocks [0,384): (b,row,half). Phase A transposes the 3x50x32 x-slab
// to LDS bf16 (row stride padded to 40 elems so ds_read_b128 runs at the
// 4-lane/bank-window floor instead of 8). Each of the 6 waves (pe,mt) builds
// its 8 MFMA A-fragments from RAW weights in registers, folding the
// parity-class reciprocal norm and the row-edge class (ho=0/191: missing
// row-tap zeroed, norm over present taps only). MFMA gives exact values for
// ALL rows; wo in {0,191} excluded by store predicates.
//
// Frame blocks [384,400): border columns wo in {0,191}, full ho 0..191,
// from an LDS-staged x column (no cache-line scatter).
//
// Tap map (ts=a*2+d), pe=0 (even ho=2s): a0->i=1 (x row s), a1->i=3 (s-1)
//                     pe=1 (odd  ho)   : a0->i=0 (s+1),     a1->i=2 (s)
// po=0 (even wo=2t): d0->j=1 (col t), d1->j=3 (t-1)
// po=1 (odd  wo)   : d0->j=0 (t+1),  d1->j=2 (t)
// ---------------------------------------------------------------------------
__global__ __launch_bounds__(384) void nct_all(
    const float* __restrict__ x,       // [2,32,96,96]
    const float* __restrict__ weight,  // [48,32,4,4]
    const float* __restrict__ bias,    // [48]
    float* __restrict__ out)           // [2,48,192,192]
{
    __shared__ __align__(16) unsigned char smem[3 * 52 * LPAD * 2];
    const int blk = blockIdx.x;
    const int tid = threadIdx.x;

    if (blk < NCBLK) {
        auto xs = (unsigned short (*)[52][LPAD])smem;   // [3][52][40] bf16

        int Wd = blk;
        const int half = Wd & 1; Wd >>= 1;
        const int row  = Wd % 96;
        const int b    = Wd / 96;
        const int c0   = half * 48;

        const int r3[3] = { (row > 0) ? row - 1 : 0, row, (row < H_IN - 1) ? row + 1 : H_IN - 1 };

        // ---- phase A: transpose 3 rows x 50 cols x 32 c into LDS ----
        // 600 items over 384 threads: item0 = tid, item1 = tid+384 (if <600).
        // All global loads for both items are issued before any packing.
        {
            const int tau0 = tid;
            const int tau1 = tid + 384;
            const bool has1 = (tau1 < 600);

            const int r0   = tau0 / 200;
            const int rem0 = tau0 - r0 * 200;
            const int pix0 = rem0 >> 2;
            const int cg0  = rem0 & 3;
            int gcol0 = c0 - 1 + pix0;
            gcol0 = (gcol0 < 0) ? 0 : ((gcol0 > W_IN - 1) ? W_IN - 1 : gcol0);
            const float* src0 = x + (size_t)(b * C_IN + cg0 * 8) * HW_IN + r3[r0] * W_IN + gcol0;

            const int tau1c = has1 ? tau1 : tau0;
            const int r1   = tau1c / 200;
            const int rem1 = tau1c - r1 * 200;
            const int pix1 = rem1 >> 2;
            const int cg1  = rem1 & 3;
            int gcol1 = c0 - 1 + pix1;
            gcol1 = (gcol1 < 0) ? 0 : ((gcol1 > W_IN - 1) ? W_IN - 1 : gcol1);
            const float* src1 = x + (size_t)(b * C_IN + cg1 * 8) * HW_IN + r3[r1] * W_IN + gcol1;

            float f0[8], f1[8];
            #pragma unroll
            for (int k = 0; k < 8; ++k) f0[k] = src0[(size_t)k * HW_IN];
            #pragma unroll
            for (int k = 0; k < 8; ++k) f1[k] = src1[(size_t)k * HW_IN];

            unsigned pk[4];
            #pragma unroll
            for (int k = 0; k < 4; ++k)
                pk[k] = (unsigned)f2bf(f0[2 * k]) | ((unsigned)f2bf(f0[2 * k + 1]) << 16);
            *(uint4*)(&xs[r0][pix0][cg0 * 8]) = make_uint4(pk[0], pk[1], pk[2], pk[3]);

            if (has1) {
                #pragma unroll
                for (int k = 0; k < 4; ++k)
                    pk[k] = (unsigned)f2bf(f1[2 * k]) | ((unsigned)f2bf(f1[2 * k + 1]) << 16);
                *(uint4*)(&xs[r1][pix1][cg1 * 8]) = make_uint4(pk[0], pk[1], pk[2], pk[3]);
            }
        }

        // ---- per-wave A-fragment build from raw weights ----
        const int lane = tid & 63;
        const int wid  = tid >> 6;     // 0..5
        const int pe = wid & 1, mt = wid >> 1;
        const int g = lane >> 4, n16 = lane & 15;

        const bool etop = (pe == 0 && row == 0);
        const bool ebot = (pe == 1 && row == H_IN - 1);
        const float m0 = ebot ? 0.f : 1.f;   // a0 tap present?
        const float m1 = etop ? 0.f : 1.f;   // a1 tap present?

        const int o = mt * 16 + n16;
        const float* wsrc = weight + ((size_t)o * C_IN + g * 8) * 16;

        bf16x8 A[2][4];
        #pragma unroll
        for (int cc = 0; cc < 8; ++cc) {
            const float4 w0 = *(const float4*)(wsrc + cc * 16);
            const float4 w1 = *(const float4*)(wsrc + cc * 16 + 4);
            const float4 w2 = *(const float4*)(wsrc + cc * 16 + 8);
            const float4 w3 = *(const float4*)(wsrc + cc * 16 + 12);
            const float4 wa0 = pe ? w0 : w1;   // a0 row taps
            const float4 wa1 = pe ? w2 : w3;   // a1 row taps

            const float r0 = 1.f / (m0 * (wa0.y + wa0.w) + m1 * (wa1.y + wa1.w)); // po=0
            const float r1 = 1.f / (m0 * (wa0.x + wa0.z) + m1 * (wa1.x + wa1.z)); // po=1

            A[0][0][cc] = (short)f2bf(m0 * wa0.y * r0);
            A[0][1][cc] = (short)f2bf(m0 * wa0.w * r0);
            A[0][2][cc] = (short)f2bf(m1 * wa1.y * r0);
            A[0][3][cc] = (short)f2bf(m1 * wa1.w * r0);
            A[1][0][cc] = (short)f2bf(m0 * wa0.x * r1);
            A[1][1][cc] = (short)f2bf(m0 * wa0.z * r1);
            A[1][2][cc] = (short)f2bf(m1 * wa1.x * r1);
            A[1][3][cc] = (short)f2bf(m1 * wa1.z * r1);
        }

        const float4 bv4 = *(const float4*)(bias + mt * 16 + 4 * g);

        __syncthreads();

        const int lr0 = pe ? 2 : 1;
        const int lr1 = pe ? 1 : 0;
        const int ho  = 2 * row + pe;

        #pragma unroll
        for (int nt = 0; nt < 3; ++nt) {
            const int lp = nt * 16 + n16 + 1;

            const bf16x8 B00 = *(const bf16x8*)(&xs[lr0][lp][g * 8]);
            const bf16x8 B0m = *(const bf16x8*)(&xs[lr0][lp - 1][g * 8]);
            const bf16x8 B0p = *(const bf16x8*)(&xs[lr0][lp + 1][g * 8]);
            const bf16x8 B10 = *(const bf16x8*)(&xs[lr1][lp][g * 8]);
            const bf16x8 B1m = *(const bf16x8*)(&xs[lr1][lp - 1][g * 8]);
            const bf16x8 B1p = *(const bf16x8*)(&xs[lr1][lp + 1][g * 8]);

            f32x4 a0 = {0.f, 0.f, 0.f, 0.f}, a1 = {0.f, 0.f, 0.f, 0.f};
            a0 = __builtin_amdgcn_mfma_f32_16x16x32_bf16(A[0][0], B00, a0, 0, 0, 0);
            a0 = __builtin_amdgcn_mfma_f32_16x16x32_bf16(A[0][1], B0m, a0, 0, 0, 0);
            a0 = __builtin_amdgcn_mfma_f32_16x16x32_bf16(A[0][2], B10, a0, 0, 0, 0);
            a0 = __builtin_amdgcn_mfma_f32_16x16x32_bf16(A[0][3], B1m, a0, 0, 0, 0);
            a1 = __builtin_amdgcn_mfma_f32_16x16x32_bf16(A[1][0], B0p, a1, 0, 0, 0);
            a1 = __builtin_amdgcn_mfma_f32_16x16x32_bf16(A[1][1], B00, a1, 0, 0, 0);
            a1 = __builtin_amdgcn_mfma_f32_16x16x32_bf16(A[1][2], B1p, a1, 0, 0, 0);
            a1 = __builtin_amdgcn_mfma_f32_16x16x32_bf16(A[1][3], B10, a1, 0, 0, 0);

            const int col = c0 + nt * 16 + n16;
            #pragma unroll
            for (int r = 0; r < 4; ++r) {
                const int oo = mt * 16 + 4 * g + r;
                const float v0 = a0[r] + bv4[r];
                const float v1 = a1[r] + bv4[r];
                float* p = out + ((size_t)(b * O_OUT + oo) * H_OUT + ho) * W_OUT + 2 * col;
                if (col == 0)             p[1] = v1;          // wo=0 is col-frame
                else if (col == W_IN - 1) p[0] = v0;          // wo=191 is col-frame
                else                      *(float2*)p = make_float2(v0, v1);
            }
        }
    } else {
        // ---- frame: border columns wo in {0,191}, ho 0..191 (corners incl.) ----
        float* xcol = (float*)smem;              // [32][96]

        const int fb   = blk - NCBLK;            // 0..15
        const int b    = fb >> 3;
        const int side = (fb >> 2) & 1;
        const int og   = fb & 3;

        const int o_loc  = tid >> 5;             // 0..11
        const int ho_loc = tid & 31;             // 0..31
        const int o      = og * 12 + o_loc;
        const int wo     = side ? 191 : 0;
        const int colx   = side ? 95 : 0;
        const int pe     = ho_loc & 1;
        const int jstar  = side ? 2 : 1;

        // stage x[:, :, :, colx] -> LDS [c][row]
        for (int idx = tid; idx < C_IN * H_IN; idx += 384) {
            const int c = idx / H_IN;
            const int r = idx - c * H_IN;
            xcol[c * H_IN + r] = x[(size_t)(b * C_IN + c) * HW_IN + r * W_IN + colx];
        }
        __syncthreads();

        int   rA[6], rB[6];
        float mBf[6];
        #pragma unroll
        for (int k = 0; k < 6; ++k) {
            const int ho = ho_loc + 32 * k;
            const int s  = ho >> 1;
            rA[k] = s;
            if (pe) { const bool m = (s + 1 < H_IN); rB[k] = m ? s + 1 : H_IN - 1; mBf[k] = m ? 1.f : 0.f; }
            else    { const bool m = (s > 0);        rB[k] = m ? s - 1 : 0;        mBf[k] = m ? 1.f : 0.f; }
        }

        const int iA = pe ? 8 : 4;    // w row-tap base for rA (i=2 / i=1)
        const int iB = pe ? 0 : 12;   // for rB (i=0 / i=3)

        float acc[6] = {0.f, 0.f, 0.f, 0.f, 0.f, 0.f};
        const float* wb = weight + (size_t)o * (C_IN * 16);

        for (int c = 0; c < C_IN; ++c) {
            const float wA = wb[c * 16 + iA + jstar];
            const float wB = wb[c * 16 + iB + jstar];
            const float rn_int  = __builtin_amdgcn_rcpf(wA + wB);
            const float rn_edge = __builtin_amdgcn_rcpf(wA);
            const float* xc = xcol + c * H_IN;
            #pragma unroll
            for (int k = 0; k < 6; ++k) {
                const float xA = xc[rA[k]];
                const float xB = xc[rB[k]];
                const float rn = (mBf[k] != 0.f) ? rn_int : rn_edge;
                acc[k] += (wA * xA + mBf[k] * (wB * xB)) * rn;
            }
        }

        const float bv = bias[o];
        #pragma unroll
        for (int k = 0; k < 6; ++k) {
            const int ho = ho_loc + 32 * k;
            out[((size_t)(b * O_OUT + o) * H_OUT + ho) * W_OUT + wo] = acc[k] + bv;
        }
    }
}

extern "C" void kernel_launch(void* const* d_in, const int* in_sizes, int n_in,
                              void* d_out, int out_size, void* d_ws, size_t ws_size,
                              hipStream_t stream) {
    const float* x    = (const float*)d_in[0];
    const float* w    = (const float*)d_in[1];
    const float* bias = (const float*)d_in[2];
    float* out = (float*)d_out;

    dim3 b384(384, 1, 1);
    dim3 gm(NCBLK + NFBLK, 1, 1);                  // 400 blocks, single launch
    hipLaunchKernelGGL(nct_all, gm, b384, 0, stream, x, w, bias, out);
}

// Round 14
// 24.894 us; speedup vs baseline: 1.1072x; 1.0610x over previous
//
#include <hip/hip_runtime.h>

#define C_IN  32
#define O_OUT 48
#define H_IN  96
#define W_IN  96
#define H_OUT 192
#define W_OUT 192
#define HW_IN (H_IN * W_IN)
#define NCBLK 192               // compute blocks: 2 b x 96 rows (both halves in-block)
#define NFBLK 16                // frame blocks: 2 b x 2 side x 4 o-groups
#define LPAD  40                // LDS row stride (elems)

typedef __attribute__((ext_vector_type(8))) short bf16x8;
typedef __attribute__((ext_vector_type(4))) float f32x4;

__device__ __forceinline__ unsigned short f2bf(float f) {
    union { float f; unsigned u; } v; v.f = f;
    unsigned u = v.u + 0x7FFFu + ((v.u >> 16) & 1u);
    return (unsigned short)(u >> 16);
}

// ---------------------------------------------------------------------------
// Single kernel, two block roles, 768-thread blocks, 208 blocks total
// (= one block-generation across 256 CUs).
//
// Compute blocks [0,192): (b,row). Phase A transposes the 3x(96+2halo)x32
// x-slab to LDS bf16: pixel index p holds global col p-1 (cols -1 and 96
// clamped). Pair-pixel float2 loads keep all vector loads 8B-aligned and
// halve VMEM instruction count. 12 waves = (half, pe, mt); each builds its
// 8 MFMA A-fragments from RAW weights in registers, folding the parity-class
// reciprocal norm and the row-edge class (ho=0/191: missing row-tap zeroed,
// norm over present taps only). MFMA gives exact values for ALL rows; wo in
// {0,191} excluded by store predicates.
//
// Frame blocks [192,208): border columns wo in {0,191}, full ho 0..191,
// from an LDS-staged x column.
//
// Tap map (ts=a*2+d), pe=0 (even ho=2s): a0->i=1 (x row s), a1->i=3 (s-1)
//                     pe=1 (odd  ho)   : a0->i=0 (s+1),     a1->i=2 (s)
// po=0 (even wo=2t): d0->j=1 (col t), d1->j=3 (t-1)
// po=1 (odd  wo)   : d0->j=0 (t+1),  d1->j=2 (t)
// ---------------------------------------------------------------------------
__global__ __launch_bounds__(768) void nct_all(
    const float* __restrict__ x,       // [2,32,96,96]
    const float* __restrict__ weight,  // [48,32,4,4]
    const float* __restrict__ bias,    // [48]
    float* __restrict__ out)           // [2,48,192,192]
{
    __shared__ __align__(16) unsigned char smem[3 * 100 * LPAD * 2];   // 24 KB
    const int blk = blockIdx.x;
    const int tid = threadIdx.x;

    if (blk < NCBLK) {
        auto xs = (unsigned short (*)[100][LPAD])smem;   // [3][100][40] bf16

        const int b   = blk / 96;
        const int row = blk % 96;

        const int r3[3] = { (row > 0) ? row - 1 : 0, row, (row < H_IN - 1) ? row + 1 : H_IN - 1 };

        // ---- phase A: transpose 3 rows x 98 pixel-cols x 32 c into LDS ----
        if (tid < 576) {
            // pair items: cols (2pp, 2pp+1) -> pix (2pp+1, 2pp+2); aligned float2
            const int r   = tid / 192;
            const int rem = tid - r * 192;
            const int pp  = rem >> 2;       // 0..47
            const int cg  = rem & 3;
            const int col = 2 * pp;
            const float* src = x + (size_t)(b * C_IN + cg * 8) * HW_IN + r3[r] * W_IN + col;
            float v0[8], v1[8];
            #pragma unroll
            for (int k = 0; k < 8; ++k) {
                const float2 v = *(const float2*)(src + (size_t)k * HW_IN);
                v0[k] = v.x; v1[k] = v.y;
            }
            unsigned p0[4], p1[4];
            #pragma unroll
            for (int k = 0; k < 4; ++k) {
                p0[k] = (unsigned)f2bf(v0[2 * k]) | ((unsigned)f2bf(v0[2 * k + 1]) << 16);
                p1[k] = (unsigned)f2bf(v1[2 * k]) | ((unsigned)f2bf(v1[2 * k + 1]) << 16);
            }
            *(uint4*)(&xs[r][col + 1][cg * 8]) = make_uint4(p0[0], p0[1], p0[2], p0[3]);
            *(uint4*)(&xs[r][col + 2][cg * 8]) = make_uint4(p1[0], p1[1], p1[2], p1[3]);
        } else if (tid < 600) {
            // halo pixels: pix 0 (col -1 -> clamp 0), pix 97 (col 96 -> clamp 95)
            const int h    = tid - 576;      // 0..23 = r(3) x side(2) x cg(4)
            const int r    = h >> 3;
            const int hs   = (h >> 2) & 1;
            const int cg   = h & 3;
            const int colx = hs ? 95 : 0;
            const int pix  = hs ? 97 : 0;
            const float* src = x + (size_t)(b * C_IN + cg * 8) * HW_IN + r3[r] * W_IN + colx;
            unsigned pk[4];
            #pragma unroll
            for (int k = 0; k < 4; ++k) {
                const float f0 = src[(size_t)(2 * k)     * HW_IN];
                const float f1 = src[(size_t)(2 * k + 1) * HW_IN];
                pk[k] = (unsigned)f2bf(f0) | ((unsigned)f2bf(f1) << 16);
            }
            *(uint4*)(&xs[r][pix][cg * 8]) = make_uint4(pk[0], pk[1], pk[2], pk[3]);
        }

        // ---- per-wave A-fragment build from raw weights ----
        const int lane = tid & 63;
        const int wid  = tid >> 6;     // 0..11
        const int half = wid / 6;
        const int sub  = wid % 6;
        const int pe = sub & 1, mt = sub >> 1;
        const int g = lane >> 4, n16 = lane & 15;
        const int c0 = half * 48;

        const bool etop = (pe == 0 && row == 0);
        const bool ebot = (pe == 1 && row == H_IN - 1);
        const float m0 = ebot ? 0.f : 1.f;   // a0 tap present?
        const float m1 = etop ? 0.f : 1.f;   // a1 tap present?

        const int o = mt * 16 + n16;
        const float* wsrc = weight + ((size_t)o * C_IN + g * 8) * 16;

        bf16x8 A[2][4];
        #pragma unroll
        for (int cc = 0; cc < 8; ++cc) {
            const float4 w0 = *(const float4*)(wsrc + cc * 16);
            const float4 w1 = *(const float4*)(wsrc + cc * 16 + 4);
            const float4 w2 = *(const float4*)(wsrc + cc * 16 + 8);
            const float4 w3 = *(const float4*)(wsrc + cc * 16 + 12);
            const float4 wa0 = pe ? w0 : w1;   // a0 row taps
            const float4 wa1 = pe ? w2 : w3;   // a1 row taps

            const float r0 = 1.f / (m0 * (wa0.y + wa0.w) + m1 * (wa1.y + wa1.w)); // po=0
            const float r1 = 1.f / (m0 * (wa0.x + wa0.z) + m1 * (wa1.x + wa1.z)); // po=1

            A[0][0][cc] = (short)f2bf(m0 * wa0.y * r0);
            A[0][1][cc] = (short)f2bf(m0 * wa0.w * r0);
            A[0][2][cc] = (short)f2bf(m1 * wa1.y * r0);
            A[0][3][cc] = (short)f2bf(m1 * wa1.w * r0);
            A[1][0][cc] = (short)f2bf(m0 * wa0.x * r1);
            A[1][1][cc] = (short)f2bf(m0 * wa0.z * r1);
            A[1][2][cc] = (short)f2bf(m1 * wa1.x * r1);
            A[1][3][cc] = (short)f2bf(m1 * wa1.z * r1);
        }

        const float4 bv4 = *(const float4*)(bias + mt * 16 + 4 * g);

        __syncthreads();

        const int lr0 = pe ? 2 : 1;
        const int lr1 = pe ? 1 : 0;
        const int ho  = 2 * row + pe;

        #pragma unroll
        for (int nt = 0; nt < 3; ++nt) {
            const int col = c0 + nt * 16 + n16;
            const int lp  = col + 1;          // pixel index in LDS

            const bf16x8 B00 = *(const bf16x8*)(&xs[lr0][lp][g * 8]);
            const bf16x8 B0m = *(const bf16x8*)(&xs[lr0][lp - 1][g * 8]);
            const bf16x8 B0p = *(const bf16x8*)(&xs[lr0][lp + 1][g * 8]);
            const bf16x8 B10 = *(const bf16x8*)(&xs[lr1][lp][g * 8]);
            const bf16x8 B1m = *(const bf16x8*)(&xs[lr1][lp - 1][g * 8]);
            const bf16x8 B1p = *(const bf16x8*)(&xs[lr1][lp + 1][g * 8]);

            f32x4 a0 = {0.f, 0.f, 0.f, 0.f}, a1 = {0.f, 0.f, 0.f, 0.f};
            a0 = __builtin_amdgcn_mfma_f32_16x16x32_bf16(A[0][0], B00, a0, 0, 0, 0);
            a0 = __builtin_amdgcn_mfma_f32_16x16x32_bf16(A[0][1], B0m, a0, 0, 0, 0);
            a0 = __builtin_amdgcn_mfma_f32_16x16x32_bf16(A[0][2], B10, a0, 0, 0, 0);
            a0 = __builtin_amdgcn_mfma_f32_16x16x32_bf16(A[0][3], B1m, a0, 0, 0, 0);
            a1 = __builtin_amdgcn_mfma_f32_16x16x32_bf16(A[1][0], B0p, a1, 0, 0, 0);
            a1 = __builtin_amdgcn_mfma_f32_16x16x32_bf16(A[1][1], B00, a1, 0, 0, 0);
            a1 = __builtin_amdgcn_mfma_f32_16x16x32_bf16(A[1][2], B1p, a1, 0, 0, 0);
            a1 = __builtin_amdgcn_mfma_f32_16x16x32_bf16(A[1][3], B10, a1, 0, 0, 0);

            #pragma unroll
            for (int r = 0; r < 4; ++r) {
                const int oo = mt * 16 + 4 * g + r;
                const float v0 = a0[r] + bv4[r];
                const float v1 = a1[r] + bv4[r];
                float* p = out + ((size_t)(b * O_OUT + oo) * H_OUT + ho) * W_OUT + 2 * col;
                if (col == 0)             p[1] = v1;          // wo=0 is col-frame
                else if (col == W_IN - 1) p[0] = v0;          // wo=191 is col-frame
                else                      *(float2*)p = make_float2(v0, v1);
            }
        }
    } else {
        // ---- frame: border columns wo in {0,191}, ho 0..191 (corners incl.) ----
        float* xcol = (float*)smem;              // [32][96]

        const int fb   = blk - NCBLK;            // 0..15
        const int b    = fb >> 3;
        const int side = (fb >> 2) & 1;
        const int og   = fb & 3;
        const int colx = side ? 95 : 0;

        // stage x[:, :, :, colx] -> LDS [c][row]
        for (int idx = tid; idx < C_IN * H_IN; idx += 768) {
            const int c = idx / H_IN;
            const int r = idx - c * H_IN;
            xcol[c * H_IN + r] = x[(size_t)(b * C_IN + c) * HW_IN + r * W_IN + colx];
        }
        __syncthreads();

        if (tid < 384) {
            const int o_loc  = tid >> 5;             // 0..11
            const int ho_loc = tid & 31;             // 0..31
            const int o      = og * 12 + o_loc;
            const int wo     = side ? 191 : 0;
            const int pe     = ho_loc & 1;
            const int jstar  = side ? 2 : 1;

            int   rA[6], rB[6];
            float mBf[6];
            #pragma unroll
            for (int k = 0; k < 6; ++k) {
                const int ho = ho_loc + 32 * k;
                const int s  = ho >> 1;
                rA[k] = s;
                if (pe) { const bool m = (s + 1 < H_IN); rB[k] = m ? s + 1 : H_IN - 1; mBf[k] = m ? 1.f : 0.f; }
                else    { const bool m = (s > 0);        rB[k] = m ? s - 1 : 0;        mBf[k] = m ? 1.f : 0.f; }
            }

            const int iA = pe ? 8 : 4;    // w row-tap base for rA (i=2 / i=1)
            const int iB = pe ? 0 : 12;   // for rB (i=0 / i=3)

            float acc[6] = {0.f, 0.f, 0.f, 0.f, 0.f, 0.f};
            const float* wb = weight + (size_t)o * (C_IN * 16);

            for (int c = 0; c < C_IN; ++c) {
                const float wA = wb[c * 16 + iA + jstar];
                const float wB = wb[c * 16 + iB + jstar];
                const float rn_int  = __builtin_amdgcn_rcpf(wA + wB);
                const float rn_edge = __builtin_amdgcn_rcpf(wA);
                const float* xc = xcol + c * H_IN;
                #pragma unroll
                for (int k = 0; k < 6; ++k) {
                    const float xA = xc[rA[k]];
                    const float xB = xc[rB[k]];
                    const float rn = (mBf[k] != 0.f) ? rn_int : rn_edge;
                    acc[k] += (wA * xA + mBf[k] * (wB * xB)) * rn;
                }
            }

            const float bv = bias[o];
            #pragma unroll
            for (int k = 0; k < 6; ++k) {
                const int ho = ho_loc + 32 * k;
                out[((size_t)(b * O_OUT + o) * H_OUT + ho) * W_OUT + wo] = acc[k] + bv;
            }
        }
    }
}

extern "C" void kernel_launch(void* const* d_in, const int* in_sizes, int n_in,
                              void* d_out, int out_size, void* d_ws, size_t ws_size,
                              hipStream_t stream) {
    const float* x    = (const float*)d_in[0];
    const float* w    = (const float*)d_in[1];
    const float* bias = (const float*)d_in[2];
    float* out = (float*)d_out;

    dim3 b768(768, 1, 1);
    dim3 gm(NCBLK + NFBLK, 1, 1);                  // 208 blocks, single launch
    hipLaunchKernelGGL(nct_all, gm, b768, 0, stream, x, w, bias, out);
}

// Round 15
// 19.657 us; speedup vs baseline: 1.4022x; 1.2664x over previous
//
#include <hip/hip_runtime.h>

#define C_IN  32
#define O_OUT 48
#define H_IN  96
#define W_IN  96
#define H_OUT 192
#define W_OUT 192
#define HW_IN (H_IN * W_IN)
#define NCBLK 192               // compute blocks: 2 b x 96 rows (both halves in-block)
#define NFBLK 16                // frame blocks: 2 b x 2 side x 4 o-groups
#define LPAD  40                // LDS row stride (elems)

typedef __attribute__((ext_vector_type(8))) short bf16x8;
typedef __attribute__((ext_vector_type(4))) float f32x4;

__device__ __forceinline__ unsigned short f2bf(float f) {
    union { float f; unsigned u; } v; v.f = f;
    unsigned u = v.u + 0x7FFFu + ((v.u >> 16) & 1u);
    return (unsigned short)(u >> 16);
}

// ---------------------------------------------------------------------------
// Single kernel, two block roles, 768-thread blocks, 208 blocks total
// (one block-generation across 256 CUs).
//
// Compute blocks [0,192): (b,row). Phase A transposes the 3x(96+2halo)x32
// x-slab to LDS bf16. 12 waves = (half, pe, mt); each builds its 8 MFMA
// A-fragments from RAW weights, loading ONLY the two row-tap float4s its
// parity needs (16 scattered VMEM/thread instead of 32 -- halves the
// 64-line/instr L1 scatter), folding the parity-class reciprocal norm and
// the row-edge class. MFMA gives exact values for ALL rows; wo in {0,191}
// excluded by store predicates.
//
// Frame blocks [192,208): border columns wo in {0,191}, full ho 0..191,
// from an LDS-staged x column.
//
// Tap map (ts=a*2+d), pe=0 (even ho=2s): a0->i=1 (x row s), a1->i=3 (s-1)
//                     pe=1 (odd  ho)   : a0->i=0 (s+1),     a1->i=2 (s)
// po=0 (even wo=2t): d0->j=1 (col t), d1->j=3 (t-1)
// po=1 (odd  wo)   : d0->j=0 (t+1),  d1->j=2 (t)
// ---------------------------------------------------------------------------
__global__ __launch_bounds__(768) void nct_all(
    const float* __restrict__ x,       // [2,32,96,96]
    const float* __restrict__ weight,  // [48,32,4,4]
    const float* __restrict__ bias,    // [48]
    float* __restrict__ out)           // [2,48,192,192]
{
    __shared__ __align__(16) unsigned char smem[3 * 100 * LPAD * 2];   // 24 KB
    const int blk = blockIdx.x;
    const int tid = threadIdx.x;

    if (blk < NCBLK) {
        auto xs = (unsigned short (*)[100][LPAD])smem;   // [3][100][40] bf16

        const int b   = blk / 96;
        const int row = blk % 96;

        const int r3[3] = { (row > 0) ? row - 1 : 0, row, (row < H_IN - 1) ? row + 1 : H_IN - 1 };

        // ---- phase A: transpose 3 rows x 98 pixel-cols x 32 c into LDS ----
        if (tid < 576) {
            // pair items: cols (2pp, 2pp+1) -> pix (2pp+1, 2pp+2); aligned float2
            const int r   = tid / 192;
            const int rem = tid - r * 192;
            const int pp  = rem >> 2;       // 0..47
            const int cg  = rem & 3;
            const int col = 2 * pp;
            const float* src = x + (size_t)(b * C_IN + cg * 8) * HW_IN + r3[r] * W_IN + col;
            float v0[8], v1[8];
            #pragma unroll
            for (int k = 0; k < 8; ++k) {
                const float2 v = *(const float2*)(src + (size_t)k * HW_IN);
                v0[k] = v.x; v1[k] = v.y;
            }
            unsigned p0[4], p1[4];
            #pragma unroll
            for (int k = 0; k < 4; ++k) {
                p0[k] = (unsigned)f2bf(v0[2 * k]) | ((unsigned)f2bf(v0[2 * k + 1]) << 16);
                p1[k] = (unsigned)f2bf(v1[2 * k]) | ((unsigned)f2bf(v1[2 * k + 1]) << 16);
            }
            *(uint4*)(&xs[r][col + 1][cg * 8]) = make_uint4(p0[0], p0[1], p0[2], p0[3]);
            *(uint4*)(&xs[r][col + 2][cg * 8]) = make_uint4(p1[0], p1[1], p1[2], p1[3]);
        } else if (tid < 600) {
            // halo pixels: pix 0 (col -1 -> clamp 0), pix 97 (col 96 -> clamp 95)
            const int h    = tid - 576;      // 0..23 = r(3) x side(2) x cg(4)
            const int r    = h >> 3;
            const int hs   = (h >> 2) & 1;
            const int cg   = h & 3;
            const int colx = hs ? 95 : 0;
            const int pix  = hs ? 97 : 0;
            const float* src = x + (size_t)(b * C_IN + cg * 8) * HW_IN + r3[r] * W_IN + colx;
            unsigned pk[4];
            #pragma unroll
            for (int k = 0; k < 4; ++k) {
                const float f0 = src[(size_t)(2 * k)     * HW_IN];
                const float f1 = src[(size_t)(2 * k + 1) * HW_IN];
                pk[k] = (unsigned)f2bf(f0) | ((unsigned)f2bf(f1) << 16);
            }
            *(uint4*)(&xs[r][pix][cg * 8]) = make_uint4(pk[0], pk[1], pk[2], pk[3]);
        }

        // ---- per-wave A-fragment build from raw weights (needed taps only) ----
        const int lane = tid & 63;
        const int wid  = tid >> 6;     // 0..11
        const int half = wid / 6;
        const int sub  = wid % 6;
        const int pe = sub & 1, mt = sub >> 1;
        const int g = lane >> 4, n16 = lane & 15;
        const int c0 = half * 48;

        const bool etop = (pe == 0 && row == 0);
        const bool ebot = (pe == 1 && row == H_IN - 1);
        const float m0 = ebot ? 0.f : 1.f;   // a0 tap present?
        const float m1 = etop ? 0.f : 1.f;   // a1 tap present?

        const int o = mt * 16 + n16;
        // wave-uniform row-tap offsets: pe=0 -> rows 1,3 (ofs 4,12); pe=1 -> rows 0,2 (ofs 0,8)
        const float* wsrc0 = weight + ((size_t)o * C_IN + g * 8) * 16 + (pe ? 0 : 4);
        const float* wsrc1 = weight + ((size_t)o * C_IN + g * 8) * 16 + (pe ? 8 : 12);

        bf16x8 A[2][4];
        #pragma unroll
        for (int cc = 0; cc < 8; ++cc) {
            const float4 wa0 = *(const float4*)(wsrc0 + cc * 16);   // a0 row taps
            const float4 wa1 = *(const float4*)(wsrc1 + cc * 16);   // a1 row taps

            const float r0 = 1.f / (m0 * (wa0.y + wa0.w) + m1 * (wa1.y + wa1.w)); // po=0
            const float r1 = 1.f / (m0 * (wa0.x + wa0.z) + m1 * (wa1.x + wa1.z)); // po=1

            A[0][0][cc] = (short)f2bf(m0 * wa0.y * r0);
            A[0][1][cc] = (short)f2bf(m0 * wa0.w * r0);
            A[0][2][cc] = (short)f2bf(m1 * wa1.y * r0);
            A[0][3][cc] = (short)f2bf(m1 * wa1.w * r0);
            A[1][0][cc] = (short)f2bf(m0 * wa0.x * r1);
            A[1][1][cc] = (short)f2bf(m0 * wa0.z * r1);
            A[1][2][cc] = (short)f2bf(m1 * wa1.x * r1);
            A[1][3][cc] = (short)f2bf(m1 * wa1.z * r1);
        }

        const float4 bv4 = *(const float4*)(bias + mt * 16 + 4 * g);

        __syncthreads();

        const int lr0 = pe ? 2 : 1;
        const int lr1 = pe ? 1 : 0;
        const int ho  = 2 * row + pe;

        #pragma unroll
        for (int nt = 0; nt < 3; ++nt) {
            const int col = c0 + nt * 16 + n16;
            const int lp  = col + 1;          // pixel index in LDS

            const bf16x8 B00 = *(const bf16x8*)(&xs[lr0][lp][g * 8]);
            const bf16x8 B0m = *(const bf16x8*)(&xs[lr0][lp - 1][g * 8]);
            const bf16x8 B0p = *(const bf16x8*)(&xs[lr0][lp + 1][g * 8]);
            const bf16x8 B10 = *(const bf16x8*)(&xs[lr1][lp][g * 8]);
            const bf16x8 B1m = *(const bf16x8*)(&xs[lr1][lp - 1][g * 8]);
            const bf16x8 B1p = *(const bf16x8*)(&xs[lr1][lp + 1][g * 8]);

            f32x4 a0 = {0.f, 0.f, 0.f, 0.f}, a1 = {0.f, 0.f, 0.f, 0.f};
            a0 = __builtin_amdgcn_mfma_f32_16x16x32_bf16(A[0][0], B00, a0, 0, 0, 0);
            a0 = __builtin_amdgcn_mfma_f32_16x16x32_bf16(A[0][1], B0m, a0, 0, 0, 0);
            a0 = __builtin_amdgcn_mfma_f32_16x16x32_bf16(A[0][2], B10, a0, 0, 0, 0);
            a0 = __builtin_amdgcn_mfma_f32_16x16x32_bf16(A[0][3], B1m, a0, 0, 0, 0);
            a1 = __builtin_amdgcn_mfma_f32_16x16x32_bf16(A[1][0], B0p, a1, 0, 0, 0);
            a1 = __builtin_amdgcn_mfma_f32_16x16x32_bf16(A[1][1], B00, a1, 0, 0, 0);
            a1 = __builtin_amdgcn_mfma_f32_16x16x32_bf16(A[1][2], B1p, a1, 0, 0, 0);
            a1 = __builtin_amdgcn_mfma_f32_16x16x32_bf16(A[1][3], B10, a1, 0, 0, 0);

            #pragma unroll
            for (int r = 0; r < 4; ++r) {
                const int oo = mt * 16 + 4 * g + r;
                const float v0 = a0[r] + bv4[r];
                const float v1 = a1[r] + bv4[r];
                float* p = out + ((size_t)(b * O_OUT + oo) * H_OUT + ho) * W_OUT + 2 * col;
                if (col == 0)             p[1] = v1;          // wo=0 is col-frame
                else if (col == W_IN - 1) p[0] = v0;          // wo=191 is col-frame
                else                      *(float2*)p = make_float2(v0, v1);
            }
        }
    } else {
        // ---- frame: border columns wo in {0,191}, ho 0..191 (corners incl.) ----
        float* xcol = (float*)smem;              // [32][96]

        const int fb   = blk - NCBLK;            // 0..15
        const int b    = fb >> 3;
        const int side = (fb >> 2) & 1;
        const int og   = fb & 3;
        const int colx = side ? 95 : 0;

        // stage x[:, :, :, colx] -> LDS [c][row]
        for (int idx = tid; idx < C_IN * H_IN; idx += 768) {
            const int c = idx / H_IN;
            const int r = idx - c * H_IN;
            xcol[c * H_IN + r] = x[(size_t)(b * C_IN + c) * HW_IN + r * W_IN + colx];
        }
        __syncthreads();

        if (tid < 384) {
            const int o_loc  = tid >> 5;             // 0..11
            const int ho_loc = tid & 31;             // 0..31
            const int o      = og * 12 + o_loc;
            const int wo     = side ? 191 : 0;
            const int pe     = ho_loc & 1;
            const int jstar  = side ? 2 : 1;

            int   rA[6], rB[6];
            float mBf[6];
            #pragma unroll
            for (int k = 0; k < 6; ++k) {
                const int ho = ho_loc + 32 * k;
                const int s  = ho >> 1;
                rA[k] = s;
                if (pe) { const bool m = (s + 1 < H_IN); rB[k] = m ? s + 1 : H_IN - 1; mBf[k] = m ? 1.f : 0.f; }
                else    { const bool m = (s > 0);        rB[k] = m ? s - 1 : 0;        mBf[k] = m ? 1.f : 0.f; }
            }

            const int iA = pe ? 8 : 4;    // w row-tap base for rA (i=2 / i=1)
            const int iB = pe ? 0 : 12;   // for rB (i=0 / i=3)

            float acc[6] = {0.f, 0.f, 0.f, 0.f, 0.f, 0.f};
            const float* wb = weight + (size_t)o * (C_IN * 16);

            for (int c = 0; c < C_IN; ++c) {
                const float wA = wb[c * 16 + iA + jstar];
                const float wB = wb[c * 16 + iB + jstar];
                const float rn_int  = __builtin_amdgcn_rcpf(wA + wB);
                const float rn_edge = __builtin_amdgcn_rcpf(wA);
                const float* xc = xcol + c * H_IN;
                #pragma unroll
                for (int k = 0; k < 6; ++k) {
                    const float xA = xc[rA[k]];
                    const float xB = xc[rB[k]];
                    const float rn = (mBf[k] != 0.f) ? rn_int : rn_edge;
                    acc[k] += (wA * xA + mBf[k] * (wB * xB)) * rn;
                }
            }

            const float bv = bias[o];
            #pragma unroll
            for (int k = 0; k < 6; ++k) {
                const int ho = ho_loc + 32 * k;
                out[((size_t)(b * O_OUT + o) * H_OUT + ho) * W_OUT + wo] = acc[k] + bv;
            }
        }
    }
}

extern "C" void kernel_launch(void* const* d_in, const int* in_sizes, int n_in,
                              void* d_out, int out_size, void* d_ws, size_t ws_size,
                              hipStream_t stream) {
    const float* x    = (const float*)d_in[0];
    const float* w    = (const float*)d_in[1];
    const float* bias = (const float*)d_in[2];
    float* out = (float*)d_out;

    dim3 b768(768, 1, 1);
    dim3 gm(NCBLK + NFBLK, 1, 1);                  // 208 blocks, single launch
    hipLaunchKernelGGL(nct_all, gm, b768, 0, stream, x, w, bias, out);
}

// Round 16
// 19.119 us; speedup vs baseline: 1.4416x; 1.0281x over previous
//
#include <hip/hip_runtime.h>

#define C_IN  32
#define O_OUT 48
#define H_IN  96
#define W_IN  96
#define H_OUT 192
#define W_OUT 192
#define HW_IN (H_IN * W_IN)
#define NCBLK 192               // compute blocks: 2 b x 96 rows (both halves in-block)
#define NFBLK 16                // frame blocks: 2 b x 2 side x 4 o-groups
#define LPAD  40                // LDS row stride (elems)
#define XS_BYTES (3 * 100 * LPAD * 2)   // 24000

typedef __attribute__((ext_vector_type(8))) short bf16x8;
typedef __attribute__((ext_vector_type(4))) float f32x4;

__device__ __forceinline__ unsigned short f2bf(float f) {
    union { float f; unsigned u; } v; v.f = f;
    unsigned u = v.u + 0x7FFFu + ((v.u >> 16) & 1u);
    return (unsigned short)(u >> 16);
}

// ---------------------------------------------------------------------------
// Single kernel, two block roles, 768-thread blocks, 208 blocks total
// (one block-generation across 256 CUs).
//
// Compute blocks [0,192): (b,row). Phase A transposes the 3x(96+2halo)x32
// x-slab to LDS bf16. A-fragments depend only on (pe,mt,row) -- NOT on the
// column half -- so only the 6 half=0 waves build them from raw weights
// (2 row-tap float4s per cc, scattered VMEM), fold the parity-class
// reciprocal norm + row-edge class, and publish the 8 fragments to LDS
// (lane-major 16B -> conflict-free). half=1 waves read them back after the
// single barrier. Halves the L1 line-scatter of the A-build (the dominant
// measured term, R14). MFMA gives exact values for ALL rows; wo in {0,191}
// excluded by store predicates.
//
// Frame blocks [192,208): border columns wo in {0,191}, full ho 0..191,
// from an LDS-staged x column.
//
// Tap map (ts=a*2+d), pe=0 (even ho=2s): a0->i=1 (x row s), a1->i=3 (s-1)
//                     pe=1 (odd  ho)   : a0->i=0 (s+1),     a1->i=2 (s)
// po=0 (even wo=2t): d0->j=1 (col t), d1->j=3 (t-1)
// po=1 (odd  wo)   : d0->j=0 (t+1),  d1->j=2 (t)
// ---------------------------------------------------------------------------
__global__ __launch_bounds__(768) void nct_all(
    const float* __restrict__ x,       // [2,32,96,96]
    const float* __restrict__ weight,  // [48,32,4,4]
    const float* __restrict__ bias,    // [48]
    float* __restrict__ out)           // [2,48,192,192]
{
    // xs: [3][100][LPAD] bf16 (24000B) | fr: [6][8][64] bf16x8 (49152B)
    __shared__ __align__(16) unsigned char smem[XS_BYTES + 6 * 8 * 64 * 16];
    const int blk = blockIdx.x;
    const int tid = threadIdx.x;

    if (blk < NCBLK) {
        auto xs = (unsigned short (*)[100][LPAD])smem;
        auto fr = (short (*)[8][64][8])(smem + XS_BYTES);

        const int b   = blk / 96;
        const int row = blk % 96;

        const int r3[3] = { (row > 0) ? row - 1 : 0, row, (row < H_IN - 1) ? row + 1 : H_IN - 1 };

        // ---- phase A: transpose 3 rows x 98 pixel-cols x 32 c into LDS ----
        if (tid < 576) {
            // pair items: cols (2pp, 2pp+1) -> pix (2pp+1, 2pp+2); aligned float2
            const int r   = tid / 192;
            const int rem = tid - r * 192;
            const int pp  = rem >> 2;       // 0..47
            const int cg  = rem & 3;
            const int col = 2 * pp;
            const float* src = x + (size_t)(b * C_IN + cg * 8) * HW_IN + r3[r] * W_IN + col;
            float v0[8], v1[8];
            #pragma unroll
            for (int k = 0; k < 8; ++k) {
                const float2 v = *(const float2*)(src + (size_t)k * HW_IN);
                v0[k] = v.x; v1[k] = v.y;
            }
            unsigned p0[4], p1[4];
            #pragma unroll
            for (int k = 0; k < 4; ++k) {
                p0[k] = (unsigned)f2bf(v0[2 * k]) | ((unsigned)f2bf(v0[2 * k + 1]) << 16);
                p1[k] = (unsigned)f2bf(v1[2 * k]) | ((unsigned)f2bf(v1[2 * k + 1]) << 16);
            }
            *(uint4*)(&xs[r][col + 1][cg * 8]) = make_uint4(p0[0], p0[1], p0[2], p0[3]);
            *(uint4*)(&xs[r][col + 2][cg * 8]) = make_uint4(p1[0], p1[1], p1[2], p1[3]);
        } else if (tid < 600) {
            // halo pixels: pix 0 (col -1 -> clamp 0), pix 97 (col 96 -> clamp 95)
            const int h    = tid - 576;      // 0..23 = r(3) x side(2) x cg(4)
            const int r    = h >> 3;
            const int hs   = (h >> 2) & 1;
            const int cg   = h & 3;
            const int colx = hs ? 95 : 0;
            const int pix  = hs ? 97 : 0;
            const float* src = x + (size_t)(b * C_IN + cg * 8) * HW_IN + r3[r] * W_IN + colx;
            unsigned pk[4];
            #pragma unroll
            for (int k = 0; k < 4; ++k) {
                const float f0 = src[(size_t)(2 * k)     * HW_IN];
                const float f1 = src[(size_t)(2 * k + 1) * HW_IN];
                pk[k] = (unsigned)f2bf(f0) | ((unsigned)f2bf(f1) << 16);
            }
            *(uint4*)(&xs[r][pix][cg * 8]) = make_uint4(pk[0], pk[1], pk[2], pk[3]);
        }

        const int lane = tid & 63;
        const int wid  = tid >> 6;     // 0..11
        const int half = wid / 6;
        const int sub  = wid % 6;
        const int pe = sub & 1, mt = sub >> 1;
        const int g = lane >> 4, n16 = lane & 15;
        const int c0 = half * 48;

        bf16x8 A[2][4];

        // ---- A-fragment build: half=0 waves only, publish to LDS ----
        if (half == 0) {
            const bool etop = (pe == 0 && row == 0);
            const bool ebot = (pe == 1 && row == H_IN - 1);
            const float m0 = ebot ? 0.f : 1.f;   // a0 tap present?
            const float m1 = etop ? 0.f : 1.f;   // a1 tap present?

            const int o = mt * 16 + n16;
            // wave-uniform row-tap offsets: pe=0 -> rows 1,3; pe=1 -> rows 0,2
            const float* wsrc0 = weight + ((size_t)o * C_IN + g * 8) * 16 + (pe ? 0 : 4);
            const float* wsrc1 = weight + ((size_t)o * C_IN + g * 8) * 16 + (pe ? 8 : 12);

            #pragma unroll
            for (int cc = 0; cc < 8; ++cc) {
                const float4 wa0 = *(const float4*)(wsrc0 + cc * 16);   // a0 row taps
                const float4 wa1 = *(const float4*)(wsrc1 + cc * 16);   // a1 row taps

                const float r0 = 1.f / (m0 * (wa0.y + wa0.w) + m1 * (wa1.y + wa1.w)); // po=0
                const float r1 = 1.f / (m0 * (wa0.x + wa0.z) + m1 * (wa1.x + wa1.z)); // po=1

                A[0][0][cc] = (short)f2bf(m0 * wa0.y * r0);
                A[0][1][cc] = (short)f2bf(m0 * wa0.w * r0);
                A[0][2][cc] = (short)f2bf(m1 * wa1.y * r0);
                A[0][3][cc] = (short)f2bf(m1 * wa1.w * r0);
                A[1][0][cc] = (short)f2bf(m0 * wa0.x * r1);
                A[1][1][cc] = (short)f2bf(m0 * wa0.z * r1);
                A[1][2][cc] = (short)f2bf(m1 * wa1.x * r1);
                A[1][3][cc] = (short)f2bf(m1 * wa1.z * r1);
            }

            #pragma unroll
            for (int po = 0; po < 2; ++po)
                #pragma unroll
                for (int ts = 0; ts < 4; ++ts)
                    *(bf16x8*)(&fr[sub][po * 4 + ts][lane][0]) = A[po][ts];
        }

        const float4 bv4 = *(const float4*)(bias + mt * 16 + 4 * g);

        __syncthreads();

        // ---- half=1 waves fetch the shared fragments (conflict-free) ----
        if (half == 1) {
            #pragma unroll
            for (int po = 0; po < 2; ++po)
                #pragma unroll
                for (int ts = 0; ts < 4; ++ts)
                    A[po][ts] = *(const bf16x8*)(&fr[sub][po * 4 + ts][lane][0]);
        }

        const int lr0 = pe ? 2 : 1;
        const int lr1 = pe ? 1 : 0;
        const int ho  = 2 * row + pe;

        #pragma unroll
        for (int nt = 0; nt < 3; ++nt) {
            const int col = c0 + nt * 16 + n16;
            const int lp  = col + 1;          // pixel index in LDS

            const bf16x8 B00 = *(const bf16x8*)(&xs[lr0][lp][g * 8]);
            const bf16x8 B0m = *(const bf16x8*)(&xs[lr0][lp - 1][g * 8]);
            const bf16x8 B0p = *(const bf16x8*)(&xs[lr0][lp + 1][g * 8]);
            const bf16x8 B10 = *(const bf16x8*)(&xs[lr1][lp][g * 8]);
            const bf16x8 B1m = *(const bf16x8*)(&xs[lr1][lp - 1][g * 8]);
            const bf16x8 B1p = *(const bf16x8*)(&xs[lr1][lp + 1][g * 8]);

            f32x4 a0 = {0.f, 0.f, 0.f, 0.f}, a1 = {0.f, 0.f, 0.f, 0.f};
            a0 = __builtin_amdgcn_mfma_f32_16x16x32_bf16(A[0][0], B00, a0, 0, 0, 0);
            a0 = __builtin_amdgcn_mfma_f32_16x16x32_bf16(A[0][1], B0m, a0, 0, 0, 0);
            a0 = __builtin_amdgcn_mfma_f32_16x16x32_bf16(A[0][2], B10, a0, 0, 0, 0);
            a0 = __builtin_amdgcn_mfma_f32_16x16x32_bf16(A[0][3], B1m, a0, 0, 0, 0);
            a1 = __builtin_amdgcn_mfma_f32_16x16x32_bf16(A[1][0], B0p, a1, 0, 0, 0);
            a1 = __builtin_amdgcn_mfma_f32_16x16x32_bf16(A[1][1], B00, a1, 0, 0, 0);
            a1 = __builtin_amdgcn_mfma_f32_16x16x32_bf16(A[1][2], B1p, a1, 0, 0, 0);
            a1 = __builtin_amdgcn_mfma_f32_16x16x32_bf16(A[1][3], B10, a1, 0, 0, 0);

            #pragma unroll
            for (int r = 0; r < 4; ++r) {
                const int oo = mt * 16 + 4 * g + r;
                const float v0 = a0[r] + bv4[r];
                const float v1 = a1[r] + bv4[r];
                float* p = out + ((size_t)(b * O_OUT + oo) * H_OUT + ho) * W_OUT + 2 * col;
                if (col == 0)             p[1] = v1;          // wo=0 is col-frame
                else if (col == W_IN - 1) p[0] = v0;          // wo=191 is col-frame
                else                      *(float2*)p = make_float2(v0, v1);
            }
        }
    } else {
        // ---- frame: border columns wo in {0,191}, ho 0..191 (corners incl.) ----
        float* xcol = (float*)smem;              // [32][96]

        const int fb   = blk - NCBLK;            // 0..15
        const int b    = fb >> 3;
        const int side = (fb >> 2) & 1;
        const int og   = fb & 3;
        const int colx = side ? 95 : 0;

        // stage x[:, :, :, colx] -> LDS [c][row]
        for (int idx = tid; idx < C_IN * H_IN; idx += 768) {
            const int c = idx / H_IN;
            const int r = idx - c * H_IN;
            xcol[c * H_IN + r] = x[(size_t)(b * C_IN + c) * HW_IN + r * W_IN + colx];
        }
        __syncthreads();

        if (tid < 384) {
            const int o_loc  = tid >> 5;             // 0..11
            const int ho_loc = tid & 31;             // 0..31
            const int o      = og * 12 + o_loc;
            const int wo     = side ? 191 : 0;
            const int pe     = ho_loc & 1;
            const int jstar  = side ? 2 : 1;

            int   rA[6], rB[6];
            float mBf[6];
            #pragma unroll
            for (int k = 0; k < 6; ++k) {
                const int ho = ho_loc + 32 * k;
                const int s  = ho >> 1;
                rA[k] = s;
                if (pe) { const bool m = (s + 1 < H_IN); rB[k] = m ? s + 1 : H_IN - 1; mBf[k] = m ? 1.f : 0.f; }
                else    { const bool m = (s > 0);        rB[k] = m ? s - 1 : 0;        mBf[k] = m ? 1.f : 0.f; }
            }

            const int iA = pe ? 8 : 4;    // w row-tap base for rA (i=2 / i=1)
            const int iB = pe ? 0 : 12;   // for rB (i=0 / i=3)

            float acc[6] = {0.f, 0.f, 0.f, 0.f, 0.f, 0.f};
            const float* wb = weight + (size_t)o * (C_IN * 16);

            for (int c = 0; c < C_IN; ++c) {
                const float wA = wb[c * 16 + iA + jstar];
                const float wB = wb[c * 16 + iB + jstar];
                const float rn_int  = __builtin_amdgcn_rcpf(wA + wB);
                const float rn_edge = __builtin_amdgcn_rcpf(wA);
                const float* xc = xcol + c * H_IN;
                #pragma unroll
                for (int k = 0; k < 6; ++k) {
                    const float xA = xc[rA[k]];
                    const float xB = xc[rB[k]];
                    const float rn = (mBf[k] != 0.f) ? rn_int : rn_edge;
                    acc[k] += (wA * xA + mBf[k] * (wB * xB)) * rn;
                }
            }

            const float bv = bias[o];
            #pragma unroll
            for (int k = 0; k < 6; ++k) {
                const int ho = ho_loc + 32 * k;
                out[((size_t)(b * O_OUT + o) * H_OUT + ho) * W_OUT + wo] = acc[k] + bv;
            }
        }
    }
}

extern "C" void kernel_launch(void* const* d_in, const int* in_sizes, int n_in,
                              void* d_out, int out_size, void* d_ws, size_t ws_size,
                              hipStream_t stream) {
    const float* x    = (const float*)d_in[0];
    const float* w    = (const float*)d_in[1];
    const float* bias = (const float*)d_in[2];
    float* out = (float*)d_out;

    dim3 b768(768, 1, 1);
    dim3 gm(NCBLK + NFBLK, 1, 1);                  // 208 blocks, single launch
    hipLaunchKernelGGL(nct_all, gm, b768, 0, stream, x, w, bias, out);
}

// Round 17
// 19.104 us; speedup vs baseline: 1.4428x; 1.0008x over previous
//
#include <hip/hip_runtime.h>

#define C_IN  32
#define O_OUT 48
#define H_IN  96
#define W_IN  96
#define H_OUT 192
#define W_OUT 192
#define HW_IN (H_IN * W_IN)
#define NCBLK 192               // compute blocks: 2 b x 96 rows (both halves in-block)
#define NFBLK 16                // frame blocks: 2 b x 2 side x 4 o-groups
#define LPAD  40                // xs row stride (elems)
#define XS_BYTES (3 * 100 * LPAD * 2)   // 24000, 16B-multiple
#define WOS   516               // weight LDS stride per o, in dwords (=2064B, packed, 16B-aligned)

typedef __attribute__((ext_vector_type(8))) short bf16x8;
typedef __attribute__((ext_vector_type(4))) float f32x4;

__device__ __forceinline__ unsigned short f2bf(float f) {
    union { float f; unsigned u; } v; v.f = f;
    unsigned u = v.u + 0x7FFFu + ((v.u >> 16) & 1u);
    return (unsigned short)(u >> 16);
}

// ---------------------------------------------------------------------------
// Single kernel, two block roles, 768-thread blocks, 208 blocks total
// (one block-generation across 256 CUs).
//
// Compute blocks [0,192): (b,row). Phase A: (1) transpose the 3x(96+2halo)x32
// x-slab to LDS bf16; (2) stage the FULL raw weight array (98KB f32) into LDS
// via perfectly-coalesced float4 loads + near-linear ds_write_b128. The
// per-wave A-fragment build then gathers its 16 float4s from LDS (b128
// gather ~12cyc) instead of scattered VMEM (64 line-fills each) -- removes
// the per-wave VMEM-scatter chain that R14 proved expensive. Fragments fold
// the parity-class reciprocal norm + row-edge class (ho=0/191). MFMA gives
// exact values for ALL rows; wo in {0,191} excluded by store predicates.
//
// Frame blocks [192,208): border columns wo in {0,191}, full ho 0..191,
// from an LDS-staged x column.
//
// Tap map (ts=a*2+d), pe=0 (even ho=2s): a0->i=1 (x row s), a1->i=3 (s-1)
//                     pe=1 (odd  ho)   : a0->i=0 (s+1),     a1->i=2 (s)
// po=0 (even wo=2t): d0->j=1 (col t), d1->j=3 (t-1)
// po=1 (odd  wo)   : d0->j=0 (t+1),  d1->j=2 (t)
// ---------------------------------------------------------------------------
__global__ __launch_bounds__(768) void nct_all(
    const float* __restrict__ x,       // [2,32,96,96]
    const float* __restrict__ weight,  // [48,32,4,4]
    const float* __restrict__ bias,    // [48]
    float* __restrict__ out)           // [2,48,192,192]
{
    // xs: [3][100][LPAD] bf16 (24000B) | wl: [48][WOS] f32 (99072B) = 123072B
    __shared__ __align__(16) unsigned char smem[XS_BYTES + O_OUT * WOS * 4];
    const int blk = blockIdx.x;
    const int tid = threadIdx.x;

    if (blk < NCBLK) {
        auto xs = (unsigned short (*)[100][LPAD])smem;
        float* wl = (float*)(smem + XS_BYTES);

        const int b   = blk / 96;
        const int row = blk % 96;

        const int r3[3] = { (row > 0) ? row - 1 : 0, row, (row < H_IN - 1) ? row + 1 : H_IN - 1 };

        // ---- phase A1: transpose 3 rows x 98 pixel-cols x 32 c into LDS ----
        if (tid < 576) {
            // pair items: cols (2pp, 2pp+1) -> pix (2pp+1, 2pp+2); aligned float2
            const int r   = tid / 192;
            const int rem = tid - r * 192;
            const int pp  = rem >> 2;       // 0..47
            const int cg  = rem & 3;
            const int col = 2 * pp;
            const float* src = x + (size_t)(b * C_IN + cg * 8) * HW_IN + r3[r] * W_IN + col;
            float v0[8], v1[8];
            #pragma unroll
            for (int k = 0; k < 8; ++k) {
                const float2 v = *(const float2*)(src + (size_t)k * HW_IN);
                v0[k] = v.x; v1[k] = v.y;
            }
            unsigned p0[4], p1[4];
            #pragma unroll
            for (int k = 0; k < 4; ++k) {
                p0[k] = (unsigned)f2bf(v0[2 * k]) | ((unsigned)f2bf(v0[2 * k + 1]) << 16);
                p1[k] = (unsigned)f2bf(v1[2 * k]) | ((unsigned)f2bf(v1[2 * k + 1]) << 16);
            }
            *(uint4*)(&xs[r][col + 1][cg * 8]) = make_uint4(p0[0], p0[1], p0[2], p0[3]);
            *(uint4*)(&xs[r][col + 2][cg * 8]) = make_uint4(p1[0], p1[1], p1[2], p1[3]);
        } else if (tid < 600) {
            // halo pixels: pix 0 (col -1 -> clamp 0), pix 97 (col 96 -> clamp 95)
            const int h    = tid - 576;      // 0..23 = r(3) x side(2) x cg(4)
            const int r    = h >> 3;
            const int hs   = (h >> 2) & 1;
            const int cg   = h & 3;
            const int colx = hs ? 95 : 0;
            const int pix  = hs ? 97 : 0;
            const float* src = x + (size_t)(b * C_IN + cg * 8) * HW_IN + r3[r] * W_IN + colx;
            unsigned pk[4];
            #pragma unroll
            for (int k = 0; k < 4; ++k) {
                const float f0 = src[(size_t)(2 * k)     * HW_IN];
                const float f1 = src[(size_t)(2 * k + 1) * HW_IN];
                pk[k] = (unsigned)f2bf(f0) | ((unsigned)f2bf(f1) << 16);
            }
            *(uint4*)(&xs[r][pix][cg * 8]) = make_uint4(pk[0], pk[1], pk[2], pk[3]);
        }

        // ---- phase A2: stage raw weights (98KB) into LDS, fully coalesced ----
        {
            const float4* wsrc = (const float4*)weight;   // 6144 float4s
            #pragma unroll
            for (int k = 0; k < 8; ++k) {
                const int f = tid + k * 768;              // 0..6143
                const int o = f >> 7;                     // f / 128
                const int m = f & 127;                    // float4 index within o
                const float4 v = wsrc[f];
                *(float4*)(wl + o * WOS + m * 4) = v;
            }
        }

        const int lane = tid & 63;
        const int wid  = tid >> 6;     // 0..11
        const int half = wid / 6;
        const int sub  = wid % 6;
        const int pe = sub & 1, mt = sub >> 1;
        const int g = lane >> 4, n16 = lane & 15;
        const int c0 = half * 48;

        const float4 bv4 = *(const float4*)(bias + mt * 16 + 4 * g);

        __syncthreads();

        // ---- A-fragment build from LDS weights (every wave, b128 gathers) ----
        const bool etop = (pe == 0 && row == 0);
        const bool ebot = (pe == 1 && row == H_IN - 1);
        const float m0 = ebot ? 0.f : 1.f;   // a0 tap present?
        const float m1 = etop ? 0.f : 1.f;   // a1 tap present?

        const int o = mt * 16 + n16;
        // dword offsets: o*WOS + (g*8+cc)*16 + rowtap*4; pe=0 -> rows 1,3; pe=1 -> rows 0,2
        const float* wb0 = wl + o * WOS + g * 128 + (pe ? 0 : 4);
        const float* wb1 = wl + o * WOS + g * 128 + (pe ? 8 : 12);

        bf16x8 A[2][4];
        #pragma unroll
        for (int cc = 0; cc < 8; ++cc) {
            const float4 wa0 = *(const float4*)(wb0 + cc * 16);   // a0 row taps
            const float4 wa1 = *(const float4*)(wb1 + cc * 16);   // a1 row taps

            const float r0 = 1.f / (m0 * (wa0.y + wa0.w) + m1 * (wa1.y + wa1.w)); // po=0
            const float r1 = 1.f / (m0 * (wa0.x + wa0.z) + m1 * (wa1.x + wa1.z)); // po=1

            A[0][0][cc] = (short)f2bf(m0 * wa0.y * r0);
            A[0][1][cc] = (short)f2bf(m0 * wa0.w * r0);
            A[0][2][cc] = (short)f2bf(m1 * wa1.y * r0);
            A[0][3][cc] = (short)f2bf(m1 * wa1.w * r0);
            A[1][0][cc] = (short)f2bf(m0 * wa0.x * r1);
            A[1][1][cc] = (short)f2bf(m0 * wa0.z * r1);
            A[1][2][cc] = (short)f2bf(m1 * wa1.x * r1);
            A[1][3][cc] = (short)f2bf(m1 * wa1.z * r1);
        }

        const int lr0 = pe ? 2 : 1;
        const int lr1 = pe ? 1 : 0;
        const int ho  = 2 * row + pe;

        #pragma unroll
        for (int nt = 0; nt < 3; ++nt) {
            const int col = c0 + nt * 16 + n16;
            const int lp  = col + 1;          // pixel index in LDS

            const bf16x8 B00 = *(const bf16x8*)(&xs[lr0][lp][g * 8]);
            const bf16x8 B0m = *(const bf16x8*)(&xs[lr0][lp - 1][g * 8]);
            const bf16x8 B0p = *(const bf16x8*)(&xs[lr0][lp + 1][g * 8]);
            const bf16x8 B10 = *(const bf16x8*)(&xs[lr1][lp][g * 8]);
            const bf16x8 B1m = *(const bf16x8*)(&xs[lr1][lp - 1][g * 8]);
            const bf16x8 B1p = *(const bf16x8*)(&xs[lr1][lp + 1][g * 8]);

            f32x4 a0 = {0.f, 0.f, 0.f, 0.f}, a1 = {0.f, 0.f, 0.f, 0.f};
            a0 = __builtin_amdgcn_mfma_f32_16x16x32_bf16(A[0][0], B00, a0, 0, 0, 0);
            a0 = __builtin_amdgcn_mfma_f32_16x16x32_bf16(A[0][1], B0m, a0, 0, 0, 0);
            a0 = __builtin_amdgcn_mfma_f32_16x16x32_bf16(A[0][2], B10, a0, 0, 0, 0);
            a0 = __builtin_amdgcn_mfma_f32_16x16x32_bf16(A[0][3], B1m, a0, 0, 0, 0);
            a1 = __builtin_amdgcn_mfma_f32_16x16x32_bf16(A[1][0], B0p, a1, 0, 0, 0);
            a1 = __builtin_amdgcn_mfma_f32_16x16x32_bf16(A[1][1], B00, a1, 0, 0, 0);
            a1 = __builtin_amdgcn_mfma_f32_16x16x32_bf16(A[1][2], B1p, a1, 0, 0, 0);
            a1 = __builtin_amdgcn_mfma_f32_16x16x32_bf16(A[1][3], B10, a1, 0, 0, 0);

            #pragma unroll
            for (int r = 0; r < 4; ++r) {
                const int oo = mt * 16 + 4 * g + r;
                const float v0 = a0[r] + bv4[r];
                const float v1 = a1[r] + bv4[r];
                float* p = out + ((size_t)(b * O_OUT + oo) * H_OUT + ho) * W_OUT + 2 * col;
                if (col == 0)             p[1] = v1;          // wo=0 is col-frame
                else if (col == W_IN - 1) p[0] = v0;          // wo=191 is col-frame
                else                      *(float2*)p = make_float2(v0, v1);
            }
        }
    } else {
        // ---- frame: border columns wo in {0,191}, ho 0..191 (corners incl.) ----
        float* xcol = (float*)smem;              // [32][96]

        const int fb   = blk - NCBLK;            // 0..15
        const int b    = fb >> 3;
        const int side = (fb >> 2) & 1;
        const int og   = fb & 3;
        const int colx = side ? 95 : 0;

        // stage x[:, :, :, colx] -> LDS [c][row]
        for (int idx = tid; idx < C_IN * H_IN; idx += 768) {
            const int c = idx / H_IN;
            const int r = idx - c * H_IN;
            xcol[c * H_IN + r] = x[(size_t)(b * C_IN + c) * HW_IN + r * W_IN + colx];
        }
        __syncthreads();

        if (tid < 384) {
            const int o_loc  = tid >> 5;             // 0..11
            const int ho_loc = tid & 31;             // 0..31
            const int o      = og * 12 + o_loc;
            const int wo     = side ? 191 : 0;
            const int pe     = ho_loc & 1;
            const int jstar  = side ? 2 : 1;

            int   rA[6], rB[6];
            float mBf[6];
            #pragma unroll
            for (int k = 0; k < 6; ++k) {
                const int ho = ho_loc + 32 * k;
                const int s  = ho >> 1;
                rA[k] = s;
                if (pe) { const bool m = (s + 1 < H_IN); rB[k] = m ? s + 1 : H_IN - 1; mBf[k] = m ? 1.f : 0.f; }
                else    { const bool m = (s > 0);        rB[k] = m ? s - 1 : 0;        mBf[k] = m ? 1.f : 0.f; }
            }

            const int iA = pe ? 8 : 4;    // w row-tap base for rA (i=2 / i=1)
            const int iB = pe ? 0 : 12;   // for rB (i=0 / i=3)

            float acc[6] = {0.f, 0.f, 0.f, 0.f, 0.f, 0.f};
            const float* wb = weight + (size_t)o * (C_IN * 16);

            for (int c = 0; c < C_IN; ++c) {
                const float wA = wb[c * 16 + iA + jstar];
                const float wB = wb[c * 16 + iB + jstar];
                const float rn_int  = __builtin_amdgcn_rcpf(wA + wB);
                const float rn_edge = __builtin_amdgcn_rcpf(wA);
                const float* xc = xcol + c * H_IN;
                #pragma unroll
                for (int k = 0; k < 6; ++k) {
                    const float xA = xc[rA[k]];
                    const float xB = xc[rB[k]];
                    const float rn = (mBf[k] != 0.f) ? rn_int : rn_edge;
                    acc[k] += (wA * xA + mBf[k] * (wB * xB)) * rn;
                }
            }

            const float bv = bias[o];
            #pragma unroll
            for (int k = 0; k < 6; ++k) {
                const int ho = ho_loc + 32 * k;
                out[((size_t)(b * O_OUT + o) * H_OUT + ho) * W_OUT + wo] = acc[k] + bv;
            }
        }
    }
}

extern "C" void kernel_launch(void* const* d_in, const int* in_sizes, int n_in,
                              void* d_out, int out_size, void* d_ws, size_t ws_size,
                              hipStream_t stream) {
    const float* x    = (const float*)d_in[0];
    const float* w    = (const float*)d_in[1];
    const float* bias = (const float*)d_in[2];
    float* out = (float*)d_out;

    dim3 b768(768, 1, 1);
    dim3 gm(NCBLK + NFBLK, 1, 1);                  // 208 blocks, single launch
    hipLaunchKernelGGL(nct_all, gm, b768, 0, stream, x, w, bias, out);
}